// Round 1
// baseline (115.150 us; speedup 1.0000x reference)
//
#include <hip/hip_runtime.h>
#include <hip/hip_bf16.h>

// Problem constants (from reference)
#define BATCH   8
#define MROWS   2048      // C*P = 4*512
#define DIM_Z   512
#define DIM_G   1024
#define EDIM    128
#define EPS     1e-6f

typedef unsigned short u16;
typedef unsigned int   u32;
typedef __attribute__((ext_vector_type(8))) short bf16x8;
typedef __attribute__((ext_vector_type(4))) float f32x4;

// f32 -> bf16 round-to-nearest-even (bit trick; inputs are finite)
__device__ __forceinline__ u16 f2b(float f) {
    u32 x = __float_as_uint(f);
    u32 r = x + 0x7fffu + ((x >> 16) & 1u);
    return (u16)(r >> 16);
}
__device__ __forceinline__ float b2f(u16 h) {
    return __uint_as_float(((u32)h) << 16);
}

// ---------------- kernel 1: u = a_emb @ Wu^T, v = a_emb @ Wv^T ----------------
__global__ void uv_kernel(const float* __restrict__ emb, const int* __restrict__ idx,
                          const float* __restrict__ Wu, const float* __restrict__ Wv,
                          float* __restrict__ u, float* __restrict__ v) {
    __shared__ float a[EDIM];
    int b = blockIdx.x;
    int t = threadIdx.x;
    if (t < EDIM) a[t] = emb[(size_t)idx[b] * EDIM + t];
    __syncthreads();
    for (int o = t; o < DIM_G + DIM_Z; o += blockDim.x) {
        const float* wrow = (o < DIM_G) ? (Wu + (size_t)o * EDIM)
                                        : (Wv + (size_t)(o - DIM_G) * EDIM);
        float s = 0.f;
#pragma unroll 8
        for (int e = 0; e < EDIM; ++e) s += a[e] * wrow[e];
        if (o < DIM_G) u[b * DIM_G + o] = s;
        else           v[b * DIM_Z + (o - DIM_G)] = s;
    }
}

// ---------------- kernel 2: cast qz f32 -> bf16 (8 elems/thread) ----------------
__global__ void cast_kernel(const float* __restrict__ in, u16* __restrict__ out, int n8) {
    int i = blockIdx.x * blockDim.x + threadIdx.x;
    if (i >= n8) return;
    const float4* p = (const float4*)in + (size_t)i * 2;
    float4 f0 = p[0], f1 = p[1];
    union { u16 us[8]; uint4 v; } o;
    o.us[0] = f2b(f0.x); o.us[1] = f2b(f0.y); o.us[2] = f2b(f0.z); o.us[3] = f2b(f0.w);
    o.us[4] = f2b(f1.x); o.us[5] = f2b(f1.y); o.us[6] = f2b(f1.z); o.us[7] = f2b(f1.w);
    ((uint4*)out)[i] = o.v;
}

// ------- kernel 3: W[b,g,d] = W_base + u*v  -> bf16, plus transposed copy -------
__global__ void wpack_kernel(const float* __restrict__ Wbase,
                             const float* __restrict__ u, const float* __restrict__ v,
                             u16* __restrict__ W, u16* __restrict__ WT) {
    __shared__ u16 tile[32][33];
    int b  = blockIdx.z;
    int g0 = blockIdx.y * 32, d0 = blockIdx.x * 32;
    int tx = threadIdx.x, ty = threadIdx.y;
#pragma unroll
    for (int j = 0; j < 4; ++j) {
        int g = g0 + ty + j * 8;
        int d = d0 + tx;
        float val = Wbase[(size_t)g * DIM_Z + d] + u[b * DIM_G + g] * v[b * DIM_Z + d];
        u16 h = f2b(val);
        W[((size_t)b * DIM_G + g) * DIM_Z + d] = h;
        tile[ty + j * 8][tx] = h;
    }
    __syncthreads();
#pragma unroll
    for (int j = 0; j < 4; ++j) {
        int d = d0 + ty + j * 8;
        int g = g0 + tx;
        WT[((size_t)b * DIM_Z + d) * DIM_G + g] = tile[tx][ty + j * 8];
    }
}

// ---------------- GEMM: C[m,n] = sum_k A[m,k] * Bt[n,k], per-batch ----------------
// EPI=0: relu -> bf16 store (qg).  EPI=1: scale by invd[m] -> f32 store (out).
// 128x128 tile, 4 waves (2x2), each wave 64x64 via 4x4 mfma_16x16x32 frags. KSTEP=64.
#define LDS_STRIDE 72   // 64 + 8 pad: row stride 144B -> bank-uniform b128 access
template <int EPI>
__global__ __launch_bounds__(256, 2)
void gemm_bt(const u16* __restrict__ Aall, const u16* __restrict__ Btall,
             void* __restrict__ Call, const float* __restrict__ invd,
             int M, int N, int K) {
    __shared__ u16 As[128 * LDS_STRIDE];
    __shared__ u16 Bs[128 * LDS_STRIDE];

    int b = blockIdx.z;
    const u16* A  = Aall  + (size_t)b * M * K;
    const u16* Bt = Btall + (size_t)b * N * K;
    int mBase = blockIdx.y * 128, nBase = blockIdx.x * 128;
    int tid  = threadIdx.x;
    int lane = tid & 63, wid = tid >> 6;
    int wm = wid >> 1, wn = wid & 1;
    int lr = lane & 15, lg = lane >> 4;

    f32x4 acc[4][4] = {};

    int rowS = tid >> 3, chunk = tid & 7;   // staging: 8 threads per 128B row-slice

    for (int kt = 0; kt < K; kt += 64) {
        __syncthreads();
#pragma unroll
        for (int p = 0; p < 4; ++p) {
            int row = p * 32 + rowS;
            *(uint4*)&As[row * LDS_STRIDE + chunk * 8] =
                *(const uint4*)(A + (size_t)(mBase + row) * K + kt + chunk * 8);
            *(uint4*)&Bs[row * LDS_STRIDE + chunk * 8] =
                *(const uint4*)(Bt + (size_t)(nBase + row) * K + kt + chunk * 8);
        }
        __syncthreads();
#pragma unroll
        for (int ks = 0; ks < 2; ++ks) {
            bf16x8 af[4], bfr[4];
#pragma unroll
            for (int mi = 0; mi < 4; ++mi)
                af[mi] = *(const bf16x8*)&As[(wm * 64 + mi * 16 + lr) * LDS_STRIDE + ks * 32 + lg * 8];
#pragma unroll
            for (int ni = 0; ni < 4; ++ni)
                bfr[ni] = *(const bf16x8*)&Bs[(wn * 64 + ni * 16 + lr) * LDS_STRIDE + ks * 32 + lg * 8];
#pragma unroll
            for (int mi = 0; mi < 4; ++mi)
#pragma unroll
                for (int ni = 0; ni < 4; ++ni)
                    acc[mi][ni] = __builtin_amdgcn_mfma_f32_16x16x32_bf16(
                        af[mi], bfr[ni], acc[mi][ni], 0, 0, 0);
        }
    }

    int mw = mBase + wm * 64, nw = nBase + wn * 64;
    if (EPI == 0) {
        u16* C = (u16*)Call + (size_t)b * M * N;
#pragma unroll
        for (int mi = 0; mi < 4; ++mi)
#pragma unroll
            for (int r = 0; r < 4; ++r) {
                int m = mw + mi * 16 + lg * 4 + r;
#pragma unroll
                for (int ni = 0; ni < 4; ++ni) {
                    int n = nw + ni * 16 + lr;
                    C[(size_t)m * N + n] = f2b(fmaxf(acc[mi][ni][r], 0.f));
                }
            }
    } else {
        float* C = (float*)Call + (size_t)b * M * N;
        const float* inv = invd + b * M;
#pragma unroll
        for (int mi = 0; mi < 4; ++mi)
#pragma unroll
            for (int r = 0; r < 4; ++r) {
                int m = mw + mi * 16 + lg * 4 + r;
                float sc = inv[m];
#pragma unroll
                for (int ni = 0; ni < 4; ++ni) {
                    int n = nw + ni * 16 + lr;
                    C[(size_t)m * N + n] = acc[mi][ni][r] * sc;
                }
            }
    }
}

// ------------- rowsum: invd[row] = 1 / max(sum_g qg[row,g], eps) -------------
// qg values are relu'd (>=0) so sum == L1 norm. One wave per row.
__global__ void rowsum_kernel(const u16* __restrict__ qg, float* __restrict__ invd) {
    int row  = blockIdx.x * 4 + (threadIdx.x >> 6);
    int lane = threadIdx.x & 63;
    const u16* p = qg + (size_t)row * DIM_G;
    float s = 0.f;
#pragma unroll
    for (int j = 0; j < 2; ++j) {
        union { uint4 v; u16 us[8]; } ld;
        ld.v = *(const uint4*)(p + (j * 64 + lane) * 8);
#pragma unroll
        for (int e = 0; e < 8; ++e) s += b2f(ld.us[e]);
    }
#pragma unroll
    for (int off = 32; off; off >>= 1) s += __shfl_xor(s, off, 64);
    if (lane == 0) invd[row] = 1.f / fmaxf(s, EPS);
}

extern "C" void kernel_launch(void* const* d_in, const int* in_sizes, int n_in,
                              void* d_out, int out_size, void* d_ws, size_t ws_size,
                              hipStream_t stream) {
    const float* qz    = (const float*)d_in[0];
    const int*   attr  = (const int*)d_in[1];
    const float* Wbase = (const float*)d_in[2];
    const float* emb   = (const float*)d_in[3];
    const float* Wu    = (const float*)d_in[4];
    const float* Wv    = (const float*)d_in[5];
    float* out = (float*)d_out;

    // workspace carve-up (all 256B aligned)
    char* ws = (char*)d_ws;
    size_t off = 0;
    auto alloc = [&](size_t bytes) -> void* {
        void* p = ws + off;
        off = (off + bytes + 255) & ~(size_t)255;
        return p;
    };
    float* u    = (float*)alloc((size_t)BATCH * DIM_G * 4);
    float* v    = (float*)alloc((size_t)BATCH * DIM_Z * 4);
    float* invd = (float*)alloc((size_t)BATCH * MROWS * 4);
    u16*   qzb  = (u16*)  alloc((size_t)BATCH * MROWS * DIM_Z * 2);
    u16*   W    = (u16*)  alloc((size_t)BATCH * DIM_G * DIM_Z * 2);
    u16*   WT   = (u16*)  alloc((size_t)BATCH * DIM_G * DIM_Z * 2);
    u16*   qg   = (u16*)  alloc((size_t)BATCH * MROWS * DIM_G * 2);
    if (off > ws_size) return;  // fail loudly (zero output) rather than corrupt

    uv_kernel<<<dim3(BATCH), dim3(256), 0, stream>>>(emb, attr, Wu, Wv, u, v);

    int n8 = BATCH * MROWS * DIM_Z / 8;
    cast_kernel<<<dim3(n8 / 256), dim3(256), 0, stream>>>(qz, qzb, n8);

    wpack_kernel<<<dim3(DIM_Z / 32, DIM_G / 32, BATCH), dim3(32, 8), 0, stream>>>(
        Wbase, u, v, W, WT);

    // GEMM1: qg[b,m,g] = relu(sum_d qz[b,m,d] * W[b,g,d])  (M=2048,N=1024,K=512)
    gemm_bt<0><<<dim3(DIM_G / 128, MROWS / 128, BATCH), dim3(256), 0, stream>>>(
        qzb, W, qg, nullptr, MROWS, DIM_G, DIM_Z);

    rowsum_kernel<<<dim3(BATCH * MROWS / 4), dim3(256), 0, stream>>>(qg, invd);

    // GEMM2: out[b,m,d] = (sum_g qg[b,m,g] * W[b,g,d]) * invd[m]  (M=2048,N=512,K=1024)
    gemm_bt<1><<<dim3(DIM_Z / 128, MROWS / 128, BATCH), dim3(256), 0, stream>>>(
        qg, WT, out, invd, MROWS, DIM_Z, DIM_G);
}

// Round 2
// 108.861 us; speedup vs baseline: 1.0578x; 1.0578x over previous
//
#include <hip/hip_runtime.h>
#include <hip/hip_bf16.h>

// Problem constants (from reference)
#define BATCH   8
#define MROWS   2048      // C*P = 4*512
#define DIM_Z   512
#define DIM_G   1024
#define EDIM    128
#define EPS     1e-6f
#define BK      64        // GEMM K-step

typedef unsigned short u16;
typedef unsigned int   u32;
typedef __attribute__((ext_vector_type(8))) short bf16x8;
typedef __attribute__((ext_vector_type(4))) float f32x4;

// f32 -> bf16 round-to-nearest-even (bit trick; inputs are finite)
__device__ __forceinline__ u16 f2b(float f) {
    u32 x = __float_as_uint(f);
    u32 r = x + 0x7fffu + ((x >> 16) & 1u);
    return (u16)(r >> 16);
}
__device__ __forceinline__ float b2f(u16 h) {
    return __uint_as_float(((u32)h) << 16);
}

// async global->LDS, 16B per lane, dest = wave-uniform base + lane*16
#define GLD16(gsrc, ldst) __builtin_amdgcn_global_load_lds( \
    (const __attribute__((address_space(1))) unsigned int*)(gsrc), \
    (__attribute__((address_space(3))) unsigned int*)(ldst), 16, 0, 0)

// ---------------- kernel 1: u = a_emb @ Wu^T, v = a_emb @ Wv^T ----------------
__global__ void uv_kernel(const float* __restrict__ emb, const int* __restrict__ idx,
                          const float* __restrict__ Wu, const float* __restrict__ Wv,
                          float* __restrict__ u, float* __restrict__ v) {
    __shared__ float a[EDIM];
    int b = blockIdx.x;
    int t = threadIdx.x;
    if (t < EDIM) a[t] = emb[(size_t)idx[b] * EDIM + t];
    __syncthreads();
    for (int o = t; o < DIM_G + DIM_Z; o += blockDim.x) {
        const float* wrow = (o < DIM_G) ? (Wu + (size_t)o * EDIM)
                                        : (Wv + (size_t)(o - DIM_G) * EDIM);
        float s = 0.f;
#pragma unroll 8
        for (int e = 0; e < EDIM; ++e) s += a[e] * wrow[e];
        if (o < DIM_G) u[b * DIM_G + o] = s;
        else           v[b * DIM_Z + (o - DIM_G)] = s;
    }
}

// ---------------- kernel 2: cast qz f32 -> bf16 (8 elems/thread) ----------------
__global__ void cast_kernel(const float* __restrict__ in, u16* __restrict__ out, int n8) {
    int i = blockIdx.x * blockDim.x + threadIdx.x;
    if (i >= n8) return;
    const float4* p = (const float4*)in + (size_t)i * 2;
    float4 f0 = p[0], f1 = p[1];
    union { u16 us[8]; uint4 v; } o;
    o.us[0] = f2b(f0.x); o.us[1] = f2b(f0.y); o.us[2] = f2b(f0.z); o.us[3] = f2b(f0.w);
    o.us[4] = f2b(f1.x); o.us[5] = f2b(f1.y); o.us[6] = f2b(f1.z); o.us[7] = f2b(f1.w);
    ((uint4*)out)[i] = o.v;
}

// ------- kernel 3: W[b,g,d] = W_base + u*v  -> bf16, plus transposed copy -------
__global__ void wpack_kernel(const float* __restrict__ Wbase,
                             const float* __restrict__ u, const float* __restrict__ v,
                             u16* __restrict__ W, u16* __restrict__ WT) {
    __shared__ u16 tile[32][33];
    int b  = blockIdx.z;
    int g0 = blockIdx.y * 32, d0 = blockIdx.x * 32;
    int tx = threadIdx.x, ty = threadIdx.y;
#pragma unroll
    for (int j = 0; j < 4; ++j) {
        int g = g0 + ty + j * 8;
        int d = d0 + tx;
        float val = Wbase[(size_t)g * DIM_Z + d] + u[b * DIM_G + g] * v[b * DIM_Z + d];
        u16 h = f2b(val);
        W[((size_t)b * DIM_G + g) * DIM_Z + d] = h;
        tile[ty + j * 8][tx] = h;
    }
    __syncthreads();
#pragma unroll
    for (int j = 0; j < 4; ++j) {
        int d = d0 + ty + j * 8;
        int g = g0 + tx;
        WT[((size_t)b * DIM_Z + d) * DIM_G + g] = tile[tx][ty + j * 8];
    }
}

// ---------------- GEMM: C[m,n] = sum_k A[m,k] * Bt[n,k], per-batch ----------------
// m97 structure: global_load_lds (width 16) staging into linear LDS; the 16B chunk
// each slot holds is XOR-swizzled on the GLOBAL SOURCE side (c = c' ^ (row&7)) and
// the same XOR is applied on the ds_read side -> bank-even b128 reads (rule #21).
// 128x128 tile, 4 waves (2x2), each wave 64x64 via 4x4 mfma_16x16x32 frags.
// EPI=0: relu -> bf16 store (qg) + per-row partial-sum atomicAdd into rsum.
// EPI=1: scale by 1/max(rsum[m],eps) -> f32 store (out).
template <int EPI>
__global__ __launch_bounds__(256, 2)
void gemm_bt(const u16* __restrict__ Aall, const u16* __restrict__ Btall,
             void* __restrict__ Call, float* __restrict__ rsum,
             int M, int N, int K) {
    __shared__ u16 As[128 * BK];   // 16KB, row-major [128][64], chunk-swizzled
    __shared__ u16 Bs[128 * BK];

    int b = blockIdx.z;
    const u16* A  = Aall  + (size_t)b * M * K;
    const u16* Bt = Btall + (size_t)b * N * K;
    int mBase = blockIdx.y * 128, nBase = blockIdx.x * 128;
    int tid  = threadIdx.x;
    int lane = tid & 63, wid = tid >> 6;
    int wm = wid >> 1, wn = wid & 1;
    int lr = lane & 15, lg = lane >> 4;

    f32x4 acc[4][4] = {};

    // staging geometry: 4 rounds per operand; round r covers slots s = r*256 + tid
    // slot s -> row = s>>3 (= r*32 + tid>>3), holds swizzled chunk c' = s&7,
    // whose global source chunk is c = c' ^ (row&7). r*32 % 8 == 0 so c is r-invariant.
    int sRow = tid >> 3;
    int sC   = (tid & 7) ^ (sRow & 7);
    const u16* aSrc = A  + (size_t)(mBase + sRow) * K + sC * 8;
    const u16* bSrc = Bt + (size_t)(nBase + sRow) * K + sC * 8;

    for (int kt = 0; kt < K; kt += BK) {
        __syncthreads();   // previous tile's reads done before overwrite
#pragma unroll
        for (int r = 0; r < 4; ++r) {
            GLD16(aSrc + (size_t)r * 32 * K + kt, &As[((r * 256 + wid * 64) * 8)]);
            GLD16(bSrc + (size_t)r * 32 * K + kt, &Bs[((r * 256 + wid * 64) * 8)]);
        }
        __syncthreads();   // compiler drains vmcnt(0) before this barrier
#pragma unroll
        for (int ks = 0; ks < 2; ++ks) {
            bf16x8 af[4], bfr[4];
#pragma unroll
            for (int mi = 0; mi < 4; ++mi) {
                int row = wm * 64 + mi * 16 + lr;
                int cq  = (ks * 4 + lg) ^ (lr & 7);
                af[mi] = *(const bf16x8*)&As[row * 64 + cq * 8];
            }
#pragma unroll
            for (int ni = 0; ni < 4; ++ni) {
                int row = wn * 64 + ni * 16 + lr;
                int cq  = (ks * 4 + lg) ^ (lr & 7);
                bfr[ni] = *(const bf16x8*)&Bs[row * 64 + cq * 8];
            }
#pragma unroll
            for (int mi = 0; mi < 4; ++mi)
#pragma unroll
                for (int ni = 0; ni < 4; ++ni)
                    acc[mi][ni] = __builtin_amdgcn_mfma_f32_16x16x32_bf16(
                        af[mi], bfr[ni], acc[mi][ni], 0, 0, 0);
        }
    }

    int mw = mBase + wm * 64, nw = nBase + wn * 64;
    if (EPI == 0) {
        u16* C = (u16*)Call + (size_t)b * M * N;
#pragma unroll
        for (int mi = 0; mi < 4; ++mi)
#pragma unroll
            for (int r = 0; r < 4; ++r) {
                int m = mw + mi * 16 + lg * 4 + r;
                float vals[4];
                float s = 0.f;
#pragma unroll
                for (int ni = 0; ni < 4; ++ni) {
                    vals[ni] = fmaxf(acc[mi][ni][r], 0.f);
                    s += vals[ni];
                }
#pragma unroll
                for (int ni = 0; ni < 4; ++ni)
                    C[(size_t)m * N + nw + ni * 16 + lr] = f2b(vals[ni]);
                // reduce across the 16 lr-lanes (same lg => same m)
                s += __shfl_xor(s, 1, 64);
                s += __shfl_xor(s, 2, 64);
                s += __shfl_xor(s, 4, 64);
                s += __shfl_xor(s, 8, 64);
                if (lr == 0) atomicAdd(&rsum[(size_t)b * M + m], s);
            }
    } else {
        float* C = (float*)Call + (size_t)b * M * N;
        const float* rs = rsum + (size_t)b * M;
#pragma unroll
        for (int mi = 0; mi < 4; ++mi)
#pragma unroll
            for (int r = 0; r < 4; ++r) {
                int m = mw + mi * 16 + lg * 4 + r;
                float inv = 1.f / fmaxf(rs[m], EPS);
#pragma unroll
                for (int ni = 0; ni < 4; ++ni)
                    C[(size_t)m * N + nw + ni * 16 + lr] = acc[mi][ni][r] * inv;
            }
    }
}

extern "C" void kernel_launch(void* const* d_in, const int* in_sizes, int n_in,
                              void* d_out, int out_size, void* d_ws, size_t ws_size,
                              hipStream_t stream) {
    const float* qz    = (const float*)d_in[0];
    const int*   attr  = (const int*)d_in[1];
    const float* Wbase = (const float*)d_in[2];
    const float* emb   = (const float*)d_in[3];
    const float* Wu    = (const float*)d_in[4];
    const float* Wv    = (const float*)d_in[5];
    float* out = (float*)d_out;

    // workspace carve-up (all 256B aligned)
    char* ws = (char*)d_ws;
    size_t off = 0;
    auto alloc = [&](size_t bytes) -> void* {
        void* p = ws + off;
        off = (off + bytes + 255) & ~(size_t)255;
        return p;
    };
    float* u    = (float*)alloc((size_t)BATCH * DIM_G * 4);
    float* v    = (float*)alloc((size_t)BATCH * DIM_Z * 4);
    float* rsum = (float*)alloc((size_t)BATCH * MROWS * 4);
    u16*   qzb  = (u16*)  alloc((size_t)BATCH * MROWS * DIM_Z * 2);
    u16*   W    = (u16*)  alloc((size_t)BATCH * DIM_G * DIM_Z * 2);
    u16*   WT   = (u16*)  alloc((size_t)BATCH * DIM_G * DIM_Z * 2);
    u16*   qg   = (u16*)  alloc((size_t)BATCH * MROWS * DIM_G * 2);
    if (off > ws_size) return;  // fail loudly (zero output) rather than corrupt

    hipMemsetAsync(rsum, 0, (size_t)BATCH * MROWS * 4, stream);

    uv_kernel<<<dim3(BATCH), dim3(256), 0, stream>>>(emb, attr, Wu, Wv, u, v);

    int n8 = BATCH * MROWS * DIM_Z / 8;
    cast_kernel<<<dim3(n8 / 256), dim3(256), 0, stream>>>(qz, qzb, n8);

    wpack_kernel<<<dim3(DIM_Z / 32, DIM_G / 32, BATCH), dim3(32, 8), 0, stream>>>(
        Wbase, u, v, W, WT);

    // GEMM1: qg[b,m,g] = relu(sum_d qz[b,m,d] * W[b,g,d]); rsum[m] += row partials
    gemm_bt<0><<<dim3(DIM_G / 128, MROWS / 128, BATCH), dim3(256), 0, stream>>>(
        qzb, W, qg, rsum, MROWS, DIM_G, DIM_Z);

    // GEMM2: out[b,m,d] = (sum_g qg[b,m,g] * W[b,g,d]) / max(rsum[m],eps)
    gemm_bt<1><<<dim3(DIM_Z / 128, MROWS / 128, BATCH), dim3(256), 0, stream>>>(
        qg, WT, out, rsum, MROWS, DIM_Z, DIM_G);
}

// Round 3
// 104.383 us; speedup vs baseline: 1.1032x; 1.0429x over previous
//
#include <hip/hip_runtime.h>
#include <hip/hip_bf16.h>

// Problem constants (from reference)
#define BATCH   8
#define MROWS   2048      // C*P = 4*512
#define DIM_Z   512
#define DIM_G   1024
#define EDIM    128
#define EPS     1e-6f
#define BK      64        // GEMM K-step

typedef unsigned short u16;
typedef unsigned int   u32;
typedef __attribute__((ext_vector_type(8))) short bf16x8;
typedef __attribute__((ext_vector_type(4))) float f32x4;

// f32 -> bf16 round-to-nearest-even (bit trick; inputs are finite)
__device__ __forceinline__ u16 f2b(float f) {
    u32 x = __float_as_uint(f);
    u32 r = x + 0x7fffu + ((x >> 16) & 1u);
    return (u16)(r >> 16);
}

// async global->LDS, 16B per lane, dest = wave-uniform base + lane*16
#define GLD16(gsrc, ldst) __builtin_amdgcn_global_load_lds( \
    (const __attribute__((address_space(1))) unsigned int*)(gsrc), \
    (__attribute__((address_space(3))) unsigned int*)(ldst), 16, 0, 0)

// ---- kernel 1: u = a_emb @ Wu^T, v = a_emb @ Wv^T (coalesced), + zero rsum ----
// grid (6, BATCH), block 256. Each block: 256 of the 1536 outputs for batch b.
// 8 outputs/pass: ty picks output row, 32 tx-lanes each take 4 strided elements
// (coalesced 128B segments), then 5-step shfl_xor reduce over the 32-lane group.
__global__ void uv_kernel(const float* __restrict__ emb, const int* __restrict__ idx,
                          const float* __restrict__ Wu, const float* __restrict__ Wv,
                          float* __restrict__ u, float* __restrict__ v,
                          float* __restrict__ rsum) {
    __shared__ float a[EDIM];
    int b = blockIdx.y;
    int t = threadIdx.x;
    if (blockIdx.x == 0)   // zero rsum[b] (runs before GEMM1 in stream order)
        for (int i = t; i < MROWS; i += 256) rsum[(size_t)b * MROWS + i] = 0.f;
    if (t < EDIM) a[t] = emb[(size_t)idx[b] * EDIM + t];
    __syncthreads();
    int tx = t & 31, ty = t >> 5;
    int oBase = blockIdx.x * 256;
    for (int o0 = 0; o0 < 256; o0 += 8) {
        int o = oBase + o0 + ty;
        const float* wrow = (o < DIM_G) ? (Wu + (size_t)o * EDIM)
                                        : (Wv + (size_t)(o - DIM_G) * EDIM);
        float s = 0.f;
#pragma unroll
        for (int q = 0; q < 4; ++q) s += a[q * 32 + tx] * wrow[q * 32 + tx];
        s += __shfl_xor(s, 1, 64);
        s += __shfl_xor(s, 2, 64);
        s += __shfl_xor(s, 4, 64);
        s += __shfl_xor(s, 8, 64);
        s += __shfl_xor(s, 16, 64);
        if (tx == 0) {
            if (o < DIM_G) u[b * DIM_G + o] = s;
            else           v[b * DIM_Z + (o - DIM_G)] = s;
        }
    }
}

// -- kernel 2: W[b,g,d] = W_base + u*v -> bf16 (+ transposed WT), all b per block --
__global__ void wpack_kernel(const float* __restrict__ Wbase,
                             const float* __restrict__ u, const float* __restrict__ v,
                             u16* __restrict__ W, u16* __restrict__ WT) {
    __shared__ u16 tile[32][33];
    int d0 = blockIdx.x * 32, g0 = blockIdx.y * 32;
    int tx = threadIdx.x, ty = threadIdx.y;
    float base[4];
#pragma unroll
    for (int j = 0; j < 4; ++j)
        base[j] = Wbase[(size_t)(g0 + ty + j * 8) * DIM_Z + d0 + tx];
    for (int b = 0; b < BATCH; ++b) {
        float vb = v[b * DIM_Z + d0 + tx];
#pragma unroll
        for (int j = 0; j < 4; ++j) {
            int g = g0 + ty + j * 8;
            u16 h = f2b(base[j] + u[b * DIM_G + g] * vb);
            W[((size_t)b * DIM_G + g) * DIM_Z + d0 + tx] = h;
            tile[ty + j * 8][tx] = h;
        }
        __syncthreads();
#pragma unroll
        for (int j = 0; j < 4; ++j)
            WT[((size_t)b * DIM_Z + d0 + ty + j * 8) * DIM_G + g0 + tx] =
                tile[tx][ty + j * 8];
        __syncthreads();   // WAR on tile before next b
    }
}

// ---------------- GEMM: C[m,n] = sum_k A[m,k] * Bt[n,k], per-batch ----------------
// B staged via global_load_lds (linear LDS dest, source chunk pre-swizzled
// c = c' ^ (row&7)); reads apply the same XOR (rule #21). A: if AF32, reg-staged
// from f32 with in-flight bf16 convert and swizzled ds_write (fused cast);
// loads issued BEFORE barrier #1 (no LDS hazard -> overlaps prev tile's MFMA).
// 128x128 tile, 4 waves (2x2), each wave 64x64 via 4x4 mfma_16x16x32 frags.
// EPI=0: relu -> bf16 store (qg) + per-row partial-sum atomicAdd into rsum.
// EPI=1: scale by 1/max(rsum[m],eps) -> f32 store (out).
template <int EPI, int AF32>
__global__ __launch_bounds__(256, 3)
void gemm_bt(const void* __restrict__ Aall, const u16* __restrict__ Btall,
             void* __restrict__ Call, float* __restrict__ rsum,
             int M, int N, int K) {
    __shared__ u16 As[128 * BK];   // 16KB, row-major [128][64], chunk-swizzled
    __shared__ u16 Bs[128 * BK];

    int b = blockIdx.z;
    const u16*   A16 = (const u16*)Aall + (size_t)b * M * K;    // AF32==0
    const float* A32 = (const float*)Aall + (size_t)b * M * K;  // AF32==1
    const u16* Bt = Btall + (size_t)b * N * K;
    int mBase = blockIdx.y * 128, nBase = blockIdx.x * 128;
    int tid  = threadIdx.x;
    int lane = tid & 63, wid = tid >> 6;
    int wm = wid >> 1, wn = wid & 1;
    int lr = lane & 15, lg = lane >> 4;

    f32x4 acc[4][4] = {};

    // staging geometry: slots s = r*256 + tid; row = s>>3 = r*32 + (tid>>3),
    // chunk-in-row c' = s&7. Swizzled chunk position cw = c ^ (row&7); since
    // r*32 % 8 == 0, row&7 == (tid>>3)&7 for all rounds.
    int sRow = tid >> 3;
    int sC   = tid & 7;
    int cw   = sC ^ (sRow & 7);
    const u16* aSrc = A16 + (size_t)(mBase + sRow) * K + cw * 8;  // pre-swizzled src
    const u16* bSrc = Bt  + (size_t)(nBase + sRow) * K + cw * 8;

    for (int kt = 0; kt < K; kt += BK) {
        float4 alo[4], ahi[4];
        if (AF32) {
#pragma unroll
            for (int r = 0; r < 4; ++r) {   // issue-early: no LDS hazard
                const float* g = A32 + (size_t)(mBase + r * 32 + sRow) * K + kt + sC * 8;
                alo[r] = *(const float4*)g;
                ahi[r] = *(const float4*)(g + 4);
            }
        }
        __syncthreads();   // previous tile's reads done before overwrite
        if (AF32) {
#pragma unroll
            for (int r = 0; r < 4; ++r)
                GLD16(bSrc + (size_t)r * 32 * K + kt, &Bs[(r * 256 + wid * 64) * 8]);
#pragma unroll
            for (int r = 0; r < 4; ++r) {
                union { u16 us[8]; uint4 v; } o;
                o.us[0] = f2b(alo[r].x); o.us[1] = f2b(alo[r].y);
                o.us[2] = f2b(alo[r].z); o.us[3] = f2b(alo[r].w);
                o.us[4] = f2b(ahi[r].x); o.us[5] = f2b(ahi[r].y);
                o.us[6] = f2b(ahi[r].z); o.us[7] = f2b(ahi[r].w);
                *(uint4*)&As[((r * 32 + sRow) * 64 + cw * 8)] = o.v;
            }
        } else {
#pragma unroll
            for (int r = 0; r < 4; ++r) {
                GLD16(aSrc + (size_t)r * 32 * K + kt, &As[(r * 256 + wid * 64) * 8]);
                GLD16(bSrc + (size_t)r * 32 * K + kt, &Bs[(r * 256 + wid * 64) * 8]);
            }
        }
        __syncthreads();   // drains vmcnt+lgkmcnt before compute
#pragma unroll
        for (int ks = 0; ks < 2; ++ks) {
            bf16x8 af[4], bfr[4];
#pragma unroll
            for (int mi = 0; mi < 4; ++mi) {
                int row = wm * 64 + mi * 16 + lr;
                int cq  = (ks * 4 + lg) ^ (lr & 7);
                af[mi] = *(const bf16x8*)&As[row * 64 + cq * 8];
            }
#pragma unroll
            for (int ni = 0; ni < 4; ++ni) {
                int row = wn * 64 + ni * 16 + lr;
                int cq  = (ks * 4 + lg) ^ (lr & 7);
                bfr[ni] = *(const bf16x8*)&Bs[row * 64 + cq * 8];
            }
#pragma unroll
            for (int mi = 0; mi < 4; ++mi)
#pragma unroll
                for (int ni = 0; ni < 4; ++ni)
                    acc[mi][ni] = __builtin_amdgcn_mfma_f32_16x16x32_bf16(
                        af[mi], bfr[ni], acc[mi][ni], 0, 0, 0);
        }
    }

    int mw = mBase + wm * 64, nw = nBase + wn * 64;
    if (EPI == 0) {
        u16* C = (u16*)Call + (size_t)b * M * N;
#pragma unroll
        for (int mi = 0; mi < 4; ++mi)
#pragma unroll
            for (int r = 0; r < 4; ++r) {
                int m = mw + mi * 16 + lg * 4 + r;
                float vals[4];
                float s = 0.f;
#pragma unroll
                for (int ni = 0; ni < 4; ++ni) {
                    vals[ni] = fmaxf(acc[mi][ni][r], 0.f);
                    s += vals[ni];
                }
#pragma unroll
                for (int ni = 0; ni < 4; ++ni)
                    C[(size_t)m * N + nw + ni * 16 + lr] = f2b(vals[ni]);
                // reduce across the 16 lr-lanes (same lg => same m)
                s += __shfl_xor(s, 1, 64);
                s += __shfl_xor(s, 2, 64);
                s += __shfl_xor(s, 4, 64);
                s += __shfl_xor(s, 8, 64);
                if (lr == 0) atomicAdd(&rsum[(size_t)b * M + m], s);
            }
    } else {
        float* C = (float*)Call + (size_t)b * M * N;
        const float* rs = rsum + (size_t)b * M;
#pragma unroll
        for (int mi = 0; mi < 4; ++mi)
#pragma unroll
            for (int r = 0; r < 4; ++r) {
                int m = mw + mi * 16 + lg * 4 + r;
                float inv = 1.f / fmaxf(rs[m], EPS);
#pragma unroll
                for (int ni = 0; ni < 4; ++ni)
                    C[(size_t)m * N + nw + ni * 16 + lr] = acc[mi][ni][r] * inv;
            }
    }
}

extern "C" void kernel_launch(void* const* d_in, const int* in_sizes, int n_in,
                              void* d_out, int out_size, void* d_ws, size_t ws_size,
                              hipStream_t stream) {
    const float* qz    = (const float*)d_in[0];
    const int*   attr  = (const int*)d_in[1];
    const float* Wbase = (const float*)d_in[2];
    const float* emb   = (const float*)d_in[3];
    const float* Wu    = (const float*)d_in[4];
    const float* Wv    = (const float*)d_in[5];
    float* out = (float*)d_out;

    // workspace carve-up (all 256B aligned)
    char* ws = (char*)d_ws;
    size_t off = 0;
    auto alloc = [&](size_t bytes) -> void* {
        void* p = ws + off;
        off = (off + bytes + 255) & ~(size_t)255;
        return p;
    };
    float* u    = (float*)alloc((size_t)BATCH * DIM_G * 4);
    float* v    = (float*)alloc((size_t)BATCH * DIM_Z * 4);
    float* rsum = (float*)alloc((size_t)BATCH * MROWS * 4);
    u16*   W    = (u16*)  alloc((size_t)BATCH * DIM_G * DIM_Z * 2);
    u16*   WT   = (u16*)  alloc((size_t)BATCH * DIM_G * DIM_Z * 2);
    u16*   qg   = (u16*)  alloc((size_t)BATCH * MROWS * DIM_G * 2);
    if (off > ws_size) return;  // fail loudly (zero output) rather than corrupt

    uv_kernel<<<dim3(6, BATCH), dim3(256), 0, stream>>>(emb, attr, Wu, Wv, u, v, rsum);

    wpack_kernel<<<dim3(DIM_Z / 32, DIM_G / 32), dim3(32, 8), 0, stream>>>(
        Wbase, u, v, W, WT);

    // GEMM1 (fused cast): qg = relu(qz_f32 @ W^T), rsum accumulated in epilogue
    gemm_bt<0, 1><<<dim3(DIM_G / 128, MROWS / 128, BATCH), dim3(256), 0, stream>>>(
        qz, W, qg, rsum, MROWS, DIM_G, DIM_Z);

    // GEMM2: out = (qg @ WT^T) / max(rsum,eps)
    gemm_bt<1, 0><<<dim3(DIM_Z / 128, MROWS / 128, BATCH), dim3(256), 0, stream>>>(
        qg, WT, out, rsum, MROWS, DIM_Z, DIM_G);
}

// Round 4
// 89.599 us; speedup vs baseline: 1.2852x; 1.1650x over previous
//
#include <hip/hip_runtime.h>
#include <hip/hip_bf16.h>

// Problem constants (from reference)
#define BATCH   8
#define MROWS   2048      // C*P = 4*512
#define DIM_Z   512
#define DIM_G   1024
#define EDIM    128
#define EPS     1e-6f
#define BK      64        // GEMM K-step

typedef unsigned short u16;
typedef unsigned int   u32;
typedef __attribute__((ext_vector_type(8))) short bf16x8;
typedef __attribute__((ext_vector_type(4))) float f32x4;

// f32 -> bf16 round-to-nearest-even (bit trick; inputs are finite)
__device__ __forceinline__ u16 f2b(float f) {
    u32 x = __float_as_uint(f);
    u32 r = x + 0x7fffu + ((x >> 16) & 1u);
    return (u16)(r >> 16);
}

// async global->LDS, 16B per lane, dest = wave-uniform base + lane*16
#define GLD16(gsrc, ldst) __builtin_amdgcn_global_load_lds( \
    (const __attribute__((address_space(1))) unsigned int*)(gsrc), \
    (__attribute__((address_space(3))) unsigned int*)(ldst), 16, 0, 0)

// ---- kernel 1: u = a_emb @ Wu^T, v = a_emb @ Wv^T (coalesced), + zero rsum ----
__global__ void uv_kernel(const float* __restrict__ emb, const int* __restrict__ idx,
                          const float* __restrict__ Wu, const float* __restrict__ Wv,
                          float* __restrict__ u, float* __restrict__ v,
                          float* __restrict__ rsum) {
    __shared__ float a[EDIM];
    int b = blockIdx.y;
    int t = threadIdx.x;
    if (blockIdx.x == 0)   // zero rsum[b] (runs before GEMM1 in stream order)
        for (int i = t; i < MROWS; i += 256) rsum[(size_t)b * MROWS + i] = 0.f;
    if (t < EDIM) a[t] = emb[(size_t)idx[b] * EDIM + t];
    __syncthreads();
    int tx = t & 31, ty = t >> 5;
    int oBase = blockIdx.x * 256;
    for (int o0 = 0; o0 < 256; o0 += 8) {
        int o = oBase + o0 + ty;
        const float* wrow = (o < DIM_G) ? (Wu + (size_t)o * EDIM)
                                        : (Wv + (size_t)(o - DIM_G) * EDIM);
        float s = 0.f;
#pragma unroll
        for (int q = 0; q < 4; ++q) s += a[q * 32 + tx] * wrow[q * 32 + tx];
        s += __shfl_xor(s, 1, 64);
        s += __shfl_xor(s, 2, 64);
        s += __shfl_xor(s, 4, 64);
        s += __shfl_xor(s, 8, 64);
        s += __shfl_xor(s, 16, 64);
        if (tx == 0) {
            if (o < DIM_G) u[b * DIM_G + o] = s;
            else           v[b * DIM_Z + (o - DIM_G)] = s;
        }
    }
}

// -- kernel 2: W[b,g,d] = W_base + u*v -> bf16 (+ transposed WT), all b per block --
__global__ void wpack_kernel(const float* __restrict__ Wbase,
                             const float* __restrict__ u, const float* __restrict__ v,
                             u16* __restrict__ W, u16* __restrict__ WT) {
    __shared__ u16 tile[32][33];
    int d0 = blockIdx.x * 32, g0 = blockIdx.y * 32;
    int tx = threadIdx.x, ty = threadIdx.y;
    float base[4];
#pragma unroll
    for (int j = 0; j < 4; ++j)
        base[j] = Wbase[(size_t)(g0 + ty + j * 8) * DIM_Z + d0 + tx];
    for (int b = 0; b < BATCH; ++b) {
        float vb = v[b * DIM_Z + d0 + tx];
#pragma unroll
        for (int j = 0; j < 4; ++j) {
            int g = g0 + ty + j * 8;
            u16 h = f2b(base[j] + u[b * DIM_G + g] * vb);
            W[((size_t)b * DIM_G + g) * DIM_Z + d0 + tx] = h;
            tile[ty + j * 8][tx] = h;
        }
        __syncthreads();
#pragma unroll
        for (int j = 0; j < 4; ++j)
            WT[((size_t)b * DIM_Z + d0 + ty + j * 8) * DIM_G + g0 + tx] =
                tile[tx][ty + j * 8];
        __syncthreads();   // WAR on tile before next b
    }
}

// ---------------- GEMM: C[m,n] = sum_k A[m,k] * Bt[n,k], per-batch ----------------
// 1D grid, XCD-aware decode: h = flat block id; b = h&7 puts each batch on one
// XCD (its 1MB B-matrix becomes L2-resident); j = h>>3 ordered n-fastest so the
// nT blocks sharing an A-panel are dispatch-adjacent (co-resident -> L2 hits).
// B staged via global_load_lds (linear LDS dest, source chunk pre-swizzled
// c = c' ^ (row&7)); reads apply the same XOR (rule #21). A: if AF32, reg-staged
// from f32 with in-flight bf16 convert and swizzled ds_write (fused cast).
// 128x128 tile, 4 waves (2x2), each wave 64x64 via 4x4 mfma_16x16x32 frags.
// EPI=0: relu -> bf16 store (qg) + per-row partial-sum atomicAdd into rsum.
// EPI=1: scale by 1/max(rsum[m],eps) -> f32 store (out).
template <int EPI, int AF32, int NTLOG>
__global__ __launch_bounds__(256, 3)
void gemm_bt(const void* __restrict__ Aall, const u16* __restrict__ Btall,
             void* __restrict__ Call, float* __restrict__ rsum,
             int M, int N, int K) {
    __shared__ u16 As[128 * BK];   // 16KB, row-major [128][64], chunk-swizzled
    __shared__ u16 Bs[128 * BK];

    int h = blockIdx.x;
    int b = h & 7;
    int j = h >> 3;
    int mBase = (j >> NTLOG) * 128;
    int nBase = (j & ((1 << NTLOG) - 1)) * 128;

    const u16*   A16 = (const u16*)Aall + (size_t)b * M * K;    // AF32==0
    const float* A32 = (const float*)Aall + (size_t)b * M * K;  // AF32==1
    const u16* Bt = Btall + (size_t)b * N * K;
    int tid  = threadIdx.x;
    int lane = tid & 63, wid = tid >> 6;
    int wm = wid >> 1, wn = wid & 1;
    int lr = lane & 15, lg = lane >> 4;

    f32x4 acc[4][4] = {};

    // staging geometry: slots s = r*256 + tid; row = s>>3 = r*32 + (tid>>3),
    // chunk-in-row c' = s&7. Swizzled chunk position cw = c ^ (row&7); since
    // r*32 % 8 == 0, row&7 == (tid>>3)&7 for all rounds.
    int sRow = tid >> 3;
    int sC   = tid & 7;
    int cw   = sC ^ (sRow & 7);
    const u16* aSrc = A16 + (size_t)(mBase + sRow) * K + cw * 8;  // pre-swizzled src
    const u16* bSrc = Bt  + (size_t)(nBase + sRow) * K + cw * 8;

    for (int kt = 0; kt < K; kt += BK) {
        float4 alo[4], ahi[4];
        if (AF32) {
#pragma unroll
            for (int r = 0; r < 4; ++r) {   // issue-early: no LDS hazard
                const float* g = A32 + (size_t)(mBase + r * 32 + sRow) * K + kt + sC * 8;
                alo[r] = *(const float4*)g;
                ahi[r] = *(const float4*)(g + 4);
            }
        }
        __syncthreads();   // previous tile's reads done before overwrite
        if (AF32) {
#pragma unroll
            for (int r = 0; r < 4; ++r)
                GLD16(bSrc + (size_t)r * 32 * K + kt, &Bs[(r * 256 + wid * 64) * 8]);
#pragma unroll
            for (int r = 0; r < 4; ++r) {
                union { u16 us[8]; uint4 v; } o;
                o.us[0] = f2b(alo[r].x); o.us[1] = f2b(alo[r].y);
                o.us[2] = f2b(alo[r].z); o.us[3] = f2b(alo[r].w);
                o.us[4] = f2b(ahi[r].x); o.us[5] = f2b(ahi[r].y);
                o.us[6] = f2b(ahi[r].z); o.us[7] = f2b(ahi[r].w);
                *(uint4*)&As[((r * 32 + sRow) * 64 + cw * 8)] = o.v;
            }
        } else {
#pragma unroll
            for (int r = 0; r < 4; ++r) {
                GLD16(aSrc + (size_t)r * 32 * K + kt, &As[(r * 256 + wid * 64) * 8]);
                GLD16(bSrc + (size_t)r * 32 * K + kt, &Bs[(r * 256 + wid * 64) * 8]);
            }
        }
        __syncthreads();   // drains vmcnt+lgkmcnt before compute
#pragma unroll
        for (int ks = 0; ks < 2; ++ks) {
            bf16x8 af[4], bfr[4];
#pragma unroll
            for (int mi = 0; mi < 4; ++mi) {
                int row = wm * 64 + mi * 16 + lr;
                int cq  = (ks * 4 + lg) ^ (lr & 7);
                af[mi] = *(const bf16x8*)&As[row * 64 + cq * 8];
            }
#pragma unroll
            for (int ni = 0; ni < 4; ++ni) {
                int row = wn * 64 + ni * 16 + lr;
                int cq  = (ks * 4 + lg) ^ (lr & 7);
                bfr[ni] = *(const bf16x8*)&Bs[row * 64 + cq * 8];
            }
#pragma unroll
            for (int mi = 0; mi < 4; ++mi)
#pragma unroll
                for (int ni = 0; ni < 4; ++ni)
                    acc[mi][ni] = __builtin_amdgcn_mfma_f32_16x16x32_bf16(
                        af[mi], bfr[ni], acc[mi][ni], 0, 0, 0);
        }
    }

    int mw = mBase + wm * 64, nw = nBase + wn * 64;
    if (EPI == 0) {
        u16* C = (u16*)Call + (size_t)b * M * N;
#pragma unroll
        for (int mi = 0; mi < 4; ++mi)
#pragma unroll
            for (int r = 0; r < 4; ++r) {
                int m = mw + mi * 16 + lg * 4 + r;
                float vals[4];
                float s = 0.f;
#pragma unroll
                for (int ni = 0; ni < 4; ++ni) {
                    vals[ni] = fmaxf(acc[mi][ni][r], 0.f);
                    s += vals[ni];
                }
#pragma unroll
                for (int ni = 0; ni < 4; ++ni)
                    C[(size_t)m * N + nw + ni * 16 + lr] = f2b(vals[ni]);
                // reduce across the 16 lr-lanes (same lg => same m)
                s += __shfl_xor(s, 1, 64);
                s += __shfl_xor(s, 2, 64);
                s += __shfl_xor(s, 4, 64);
                s += __shfl_xor(s, 8, 64);
                if (lr == 0) atomicAdd(&rsum[(size_t)b * M + m], s);
            }
    } else {
        float* C = (float*)Call + (size_t)b * M * N;
        const float* rs = rsum + (size_t)b * M;
#pragma unroll
        for (int mi = 0; mi < 4; ++mi)
#pragma unroll
            for (int r = 0; r < 4; ++r) {
                int m = mw + mi * 16 + lg * 4 + r;
                float inv = 1.f / fmaxf(rs[m], EPS);
#pragma unroll
                for (int ni = 0; ni < 4; ++ni)
                    C[(size_t)m * N + nw + ni * 16 + lr] = acc[mi][ni][r] * inv;
            }
    }
}

extern "C" void kernel_launch(void* const* d_in, const int* in_sizes, int n_in,
                              void* d_out, int out_size, void* d_ws, size_t ws_size,
                              hipStream_t stream) {
    const float* qz    = (const float*)d_in[0];
    const int*   attr  = (const int*)d_in[1];
    const float* Wbase = (const float*)d_in[2];
    const float* emb   = (const float*)d_in[3];
    const float* Wu    = (const float*)d_in[4];
    const float* Wv    = (const float*)d_in[5];
    float* out = (float*)d_out;

    // workspace carve-up (all 256B aligned)
    char* ws = (char*)d_ws;
    size_t off = 0;
    auto alloc = [&](size_t bytes) -> void* {
        void* p = ws + off;
        off = (off + bytes + 255) & ~(size_t)255;
        return p;
    };
    float* u    = (float*)alloc((size_t)BATCH * DIM_G * 4);
    float* v    = (float*)alloc((size_t)BATCH * DIM_Z * 4);
    float* rsum = (float*)alloc((size_t)BATCH * MROWS * 4);
    u16*   W    = (u16*)  alloc((size_t)BATCH * DIM_G * DIM_Z * 2);
    u16*   WT   = (u16*)  alloc((size_t)BATCH * DIM_G * DIM_Z * 2);
    u16*   qg   = (u16*)  alloc((size_t)BATCH * MROWS * DIM_G * 2);
    if (off > ws_size) return;  // fail loudly (zero output) rather than corrupt

    uv_kernel<<<dim3(6, BATCH), dim3(256), 0, stream>>>(emb, attr, Wu, Wv, u, v, rsum);

    wpack_kernel<<<dim3(DIM_Z / 32, DIM_G / 32), dim3(32, 8), 0, stream>>>(
        Wbase, u, v, W, WT);

    // GEMM1 (fused cast): qg = relu(qz_f32 @ W^T), rsum accumulated in epilogue
    // grid: 8 nT * 16 mT * 8 b = 1024 blocks, XCD-decoded in-kernel
    gemm_bt<0, 1, 3><<<dim3(1024), dim3(256), 0, stream>>>(
        qz, W, qg, rsum, MROWS, DIM_G, DIM_Z);

    // GEMM2: out = (qg @ WT^T) / max(rsum,eps)   (4 nT * 16 mT * 8 b = 512 blocks)
    gemm_bt<1, 0, 2><<<dim3(512), dim3(256), 0, stream>>>(
        qg, WT, out, rsum, MROWS, DIM_Z, DIM_G);
}